// Round 5
// baseline (341.576 us; speedup 1.0000x reference)
//
#include <hip/hip_runtime.h>
#include <math.h>

#define B_   4
#define N_   4096
#define D_   1024
#define DFF_ 4096
#define K_   2048

typedef __attribute__((ext_vector_type(8))) short short8;
typedef __attribute__((ext_vector_type(4))) float float4v;

__device__ __forceinline__ unsigned short f2bf(float f) {
    unsigned int u = __float_as_uint(f);
    u = (u + 0x7fffu + ((u >> 16) & 1u)) >> 16;   // RNE
    return (unsigned short)u;
}

__device__ __forceinline__ void gld16(const void* g, void* l) {
    __builtin_amdgcn_global_load_lds((const __attribute__((address_space(1))) void*)g,
                                     (__attribute__((address_space(3))) void*)l, 16, 0, 0);
}

// ---------------- scores (bit-identical selection math) + slot clear ----------------
__global__ __launch_bounds__(256) void scores_kernel(const float* __restrict__ x,
                                                     const float* __restrict__ gate_w,
                                                     float* __restrict__ scores,
                                                     int* __restrict__ slot) {
    int wave = (blockIdx.x * blockDim.x + threadIdx.x) >> 6;
    int lane = threadIdx.x & 63;
    if (wave >= B_ * N_) return;
    if (lane == 1) slot[wave] = -1;
    const float4* xr = (const float4*)(x + (size_t)wave * D_);
    const float4* g  = (const float4*)gate_w;
    float acc = 0.f;
    #pragma unroll
    for (int j = 0; j < D_ / 4 / 64; ++j) {
        float4 a = xr[lane + j * 64];
        float4 b = g[lane + j * 64];
        acc += a.x * b.x + a.y * b.y + a.z * b.z + a.w * b.w;
    }
    #pragma unroll
    for (int off = 32; off > 0; off >>= 1) acc += __shfl_down(acc, off, 64);
    if (lane == 0) scores[wave] = acc;
}

// ---------------- top-k radix select, wave-level scans; writes topk + global slot map ----------------
__global__ __launch_bounds__(1024) void select_topk_kernel(const float* __restrict__ scores,
                                                           int* __restrict__ topk,
                                                           int* __restrict__ slot) {
    __shared__ unsigned key[N_];
    __shared__ unsigned hist[256];
    __shared__ int sh_bin, sh_rem, sh_ngt;
    __shared__ int wsum[16], woff[16];
    int b = blockIdx.x, tid = threadIdx.x;
    int lane = tid & 63, wid = tid >> 6;

    for (int i = tid; i < N_; i += 1024) {
        unsigned u = __float_as_uint(scores[b * N_ + i]);
        key[i] = (u & 0x80000000u) ? ~u : (u | 0x80000000u);   // monotonic map
    }
    if (tid == 0) sh_ngt = 0;
    __syncthreads();

    unsigned prefix = 0, pmask = 0;
    int rem = K_;
    for (int shift = 24; shift >= 0; shift -= 8) {
        if (tid < 256) hist[tid] = 0;
        __syncthreads();
        for (int i = tid; i < N_; i += 1024) {
            unsigned k = key[i];
            if ((k & pmask) == prefix) atomicAdd(&hist[(k >> shift) & 255u], 1u);
        }
        __syncthreads();
        if (tid < 64) {   // wave 0: suffix scan of 256 bins, 4 bins/lane
            unsigned v0 = hist[4 * lane], v1 = hist[4 * lane + 1];
            unsigned v2 = hist[4 * lane + 2], v3 = hist[4 * lane + 3];
            unsigned s3 = v3, s2 = v2 + s3, s1 = v1 + s2, s0 = v0 + s1;
            unsigned t = s0;
            #pragma unroll
            for (int off = 1; off < 64; off <<= 1) {
                unsigned u = __shfl_down(t, off, 64);
                if (lane + off < 64) t += u;
            }
            unsigned above = t - s0;                  // keys in bins > 4*lane+3
            unsigned S0 = s0 + above, S1 = s1 + above, S2 = s2 + above, S3 = s3 + above;
            unsigned R = (unsigned)rem;
            if (S0 >= R && S1 < R) { sh_bin = 4 * lane;     sh_rem = rem - (int)S1; }
            if (S1 >= R && S2 < R) { sh_bin = 4 * lane + 1; sh_rem = rem - (int)S2; }
            if (S2 >= R && S3 < R) { sh_bin = 4 * lane + 2; sh_rem = rem - (int)S3; }
            if (S3 >= R && above < R) { sh_bin = 4 * lane + 3; sh_rem = rem - (int)above; }
        }
        __syncthreads();
        prefix |= ((unsigned)sh_bin) << shift;
        pmask  |= 0xffu << shift;
        rem = sh_rem;
    }
    unsigned T = prefix;          // exact key of k-th largest
    int c_gt = K_ - rem;          // count strictly greater

    // strictly-greater: ballot-compacted, arbitrary order, slots [0, c_gt)
    for (int i = tid; i < N_; i += 1024) {
        bool p = key[i] > T;
        unsigned long long m = __ballot(p);
        int cnt = __popcll(m);
        int basepos = 0;
        if (lane == 0 && cnt) basepos = atomicAdd(&sh_ngt, cnt);
        basepos = __shfl(basepos, 0, 64);
        if (p) {
            int pos = basepos + __popcll(m & ((1ULL << lane) - 1ULL));
            topk[b * K_ + pos] = i;
            slot[b * N_ + i] = b * K_ + pos;
        }
    }
    // ties: first `rem` by index -> slots [c_gt, K)
    int base = tid * 4, c = 0;
    #pragma unroll
    for (int j = 0; j < 4; ++j) c += (key[base + j] == T);
    int sc = c;
    #pragma unroll
    for (int off = 1; off < 64; off <<= 1) {
        int u = __shfl_up(sc, off, 64);
        if (lane >= off) sc += u;
    }
    if (lane == 63) wsum[wid] = sc;
    __syncthreads();
    if (tid == 0) {
        int run = 0;
        #pragma unroll
        for (int j = 0; j < 16; ++j) { woff[j] = run; run += wsum[j]; }
    }
    __syncthreads();
    int r = woff[wid] + sc - c;   // exclusive prefix among ties
    #pragma unroll
    for (int j = 0; j < 4; ++j) {
        if (key[base + j] == T) {
            if (r < rem) {
                topk[b * K_ + c_gt + r] = base + j;
                slot[b * N_ + base + j] = b * K_ + c_gt + r;
            }
            ++r;
        }
    }
}

// ---------------- fused: selected rows -> bf16 xsel[slot]; unselected -> out copy ----------------
__global__ __launch_bounds__(256) void gather_copy_kernel(const float* __restrict__ x,
                                                          const int* __restrict__ slot,
                                                          unsigned short* __restrict__ xsel,
                                                          float* __restrict__ out) {
    int row = blockIdx.x;
    int t = threadIdx.x;
    int s = slot[row];
    float4 v = ((const float4*)(x + (size_t)row * D_))[t];
    if (s >= 0) {
        ushort4 o;
        o.x = f2bf(v.x); o.y = f2bf(v.y); o.z = f2bf(v.z); o.w = f2bf(v.w);
        ((ushort4*)(xsel + (size_t)s * D_))[t] = o;
    } else {
        ((float4*)(out + (size_t)row * D_))[t] = v;
    }
}

// ---------------- both weight transposes (fp32 [R][C] -> bf16 [C][R]) in one launch ----------------
__global__ __launch_bounds__(256) void transpose_both_kernel(const float* __restrict__ w1,
                                                             const float* __restrict__ w2,
                                                             unsigned short* __restrict__ w1t,
                                                             unsigned short* __restrict__ w2t) {
    __shared__ float tile[32][33];
    int bid = blockIdx.x;
    const float* src; unsigned short* dst; int R, C, bx, by;
    if (bid < 4096) { src = w1; dst = w1t; R = D_;   C = DFF_; bx = bid & 127;          by = bid >> 7; }
    else            { src = w2; dst = w2t; R = DFF_; C = D_;   bx = (bid - 4096) & 31;  by = (bid - 4096) >> 5; }
    int tx = threadIdx.x & 31, ty = threadIdx.x >> 5;   // 32 x 8
    int c = bx * 32 + tx, r0 = by * 32;
    #pragma unroll
    for (int j = ty; j < 32; j += 8) tile[j][tx] = src[(size_t)(r0 + j) * C + c];
    __syncthreads();
    int dc = by * 32 + tx, dr0 = bx * 32;
    #pragma unroll
    for (int j = ty; j < 32; j += 8) dst[(size_t)(dr0 + j) * R + dc] = f2bf(tile[tx][j]);
}

// ======== row-pair XOR swizzle (verified r3: conflicts -> 0) ========
// Row = 32 shorts (4 x 16B chunks). Logical chunk (r, kc) stored at chunk index
// (r>>1)*8 + ((((r&1)<<2)|kc) ^ ((r>>1)&7)). LDS dest linear for global_load_lds;
// permutation applied to global source + ds_read address (same involution).

// ---------------- MFMA GEMM 1 (wave 128x64): h1 = gelu(x_sel @ w1 + b1) ----------------
// 256x128 tile, BK=32, 256 thr (4 waves 2Mx2N, 128x64/wave: 8 A-frags x 4 B-frags),
// dbuf 48 KiB -> 2 blocks/CU; 12 ds_read + 32 MFMA per phase (LDS reads/FLOP -25% vs 64x64);
// XCD-chunked swizzle: each XCD owns 4 consecutive row-panels (A pinned in L2, B streamed).
__global__ __launch_bounds__(256, 2) void ffn1_w128_kernel(const unsigned short* __restrict__ A,
                                                           const unsigned short* __restrict__ Bt,
                                                           const float* __restrict__ b1,
                                                           unsigned short* __restrict__ h1) {
    constexpr int K  = D_;        // 1024
    constexpr int NT = K / 32;    // 32 K-tiles
    __shared__ __align__(16) unsigned short smem[24576];   // 48 KiB: 2 x (A 8192 | B 4096 shorts)

    const int t    = threadIdx.x;
    const int lane = t & 63;
    const int wid  = t >> 6;
    const int quad = lane >> 4;
    const int lr   = lane & 15;
    const int wr   = wid >> 1;            // 0..1  (M, 128 rows)
    const int wc   = wid & 1;             // 0..1  (N, 64 cols)
    // XCD swizzle: grid 1024 (1D); XCD k (bid%8) gets L in [128k,128k+128) = x in [4k,4k+4), all 32 y.
    const int L    = (blockIdx.x & 7) * 128 + (blockIdx.x >> 3);
    const int row0 = (L >> 5) * 256;
    const int col0 = (L & 31) * 128;

    // staging: A = 1024 chunks (thread t -> t+j*256, j=0..3), B = 512 chunks (j=0..1)
    const char* aS[4]; int oA[4];
    const char* bS[2]; int oB[2];
    #pragma unroll
    for (int j = 0; j < 4; ++j) {
        int s = t + j * 256;
        int rp = s >> 3, w = (s & 7) ^ (rp & 7);
        aS[j] = (const char*)A + ((size_t)(row0 + rp * 2 + (w >> 2)) * K + (size_t)(w & 3) * 8) * 2;
        oA[j] = s * 8;
    }
    #pragma unroll
    for (int j = 0; j < 2; ++j) {
        int s = t + j * 256;
        int rp = s >> 3, w = (s & 7) ^ (rp & 7);
        bS[j] = (const char*)Bt + ((size_t)(col0 + rp * 2 + (w >> 2)) * K + (size_t)(w & 3) * 8) * 2;
        oB[j] = 8192 + s * 8;
    }

    // fragment bases (swizzled); mi/ni advance 16 rows = +512 shorts (row-pair mod-8 invariant)
    const int rbA = wr * 128 + lr, rA2 = rbA >> 1;
    const int aoff = (rA2 * 8 + ((((rbA & 1) << 2) | quad) ^ (rA2 & 7))) * 8;
    const int rbB = wc * 64 + lr, rB2 = rbB >> 1;
    const int boff = 8192 + (rB2 * 8 + ((((rbB & 1) << 2) | quad) ^ (rB2 & 7))) * 8;

    unsigned short* lds0 = smem;
    unsigned short* lds1 = smem + 12288;

    // ---- prologue: stage K-tile 0 ----
    #pragma unroll
    for (int j = 0; j < 4; ++j) gld16(aS[j], lds0 + oA[j]);
    #pragma unroll
    for (int j = 0; j < 2; ++j) gld16(bS[j], lds0 + oB[j]);
    #pragma unroll
    for (int j = 0; j < 4; ++j) aS[j] += 64;
    #pragma unroll
    for (int j = 0; j < 2; ++j) bS[j] += 64;
    asm volatile("s_waitcnt vmcnt(0)" ::: "memory");
    __builtin_amdgcn_s_barrier();

    float4v acc[8][4] = {};

    auto step = [&](const unsigned short* cur, unsigned short* nxt, bool pf) {
        short8 af[8], bq[4];
        #pragma unroll
        for (int mi = 0; mi < 8; ++mi) af[mi] = *(const short8*)(cur + aoff + mi * 512);
        #pragma unroll
        for (int ni = 0; ni < 4; ++ni) bq[ni] = *(const short8*)(cur + boff + ni * 512);
        if (pf) {
            #pragma unroll
            for (int j = 0; j < 4; ++j) gld16(aS[j], nxt + oA[j]);
            #pragma unroll
            for (int j = 0; j < 2; ++j) gld16(bS[j], nxt + oB[j]);
            #pragma unroll
            for (int j = 0; j < 4; ++j) aS[j] += 64;
            #pragma unroll
            for (int j = 0; j < 2; ++j) bS[j] += 64;
        }
        __builtin_amdgcn_sched_barrier(0);
        __builtin_amdgcn_s_setprio(1);
        #pragma unroll
        for (int mi = 0; mi < 8; ++mi)
            #pragma unroll
            for (int ni = 0; ni < 4; ++ni)
                acc[mi][ni] = __builtin_amdgcn_mfma_f32_16x16x32_bf16(af[mi], bq[ni], acc[mi][ni], 0, 0, 0);
        __builtin_amdgcn_s_setprio(0);
        asm volatile("s_waitcnt vmcnt(0)" ::: "memory");   // next tile landed (hidden under MFMA)
        __builtin_amdgcn_s_barrier();
    };

    for (int kt = 0; kt < NT - 2; kt += 2) { step(lds0, lds1, true); step(lds1, lds0, true); }
    step(lds0, lds1, true);    // kt = NT-2
    step(lds1, lds0, false);   // kt = NT-1 (trailing barrier guards smem reuse)

    // ---- epilogue: bias+GELU -> bf16 via per-wave LDS (16 rows x 66 shorts), full-128B-line stores ----
    float bias[4];
    #pragma unroll
    for (int ni = 0; ni < 4; ++ni) bias[ni] = b1[col0 + wc * 64 + ni * 16 + lr];
    unsigned short* ws_ = smem + wid * 1056;   // 4 waves x 1056 shorts
    const int co = col0 + wc * 64;
    #pragma unroll
    for (int mi = 0; mi < 8; ++mi) {
        const int ro = row0 + wr * 128 + mi * 16;
        #pragma unroll
        for (int ni = 0; ni < 4; ++ni)
            #pragma unroll
            for (int r = 0; r < 4; ++r) {
                float u = acc[mi][ni][r] + bias[ni];
                float tt = 1.5957691216057308f * u * (1.0f + 0.044715f * u * u);
                float g = u / (1.0f + __expf(-tt));
                ws_[(quad * 4 + r) * 66 + ni * 16 + lr] = f2bf(g);
            }
        asm volatile("s_waitcnt lgkmcnt(0)" ::: "memory");
        #pragma unroll
        for (int j = 0; j < 2; ++j) {
            int chk = lane + j * 64;          // 128 chunks = 16 rows x 8 x 16B
            int rr = chk >> 3, cc = chk & 7;
            *(short8*)(h1 + (size_t)(ro + rr) * DFF_ + co + cc * 8) =
                *(const short8*)(ws_ + rr * 66 + cc * 8);
        }
        asm volatile("s_waitcnt lgkmcnt(0)" ::: "memory");
    }
}

// ---------------- MFMA GEMM 2 (BK=64, dbuf, 2 blocks/CU): out[sel] = x_sel + h1 @ w2 + b2 ----------------
// 128x128 tile, 256 thr (4 waves 2x2, 64x64/wave); XCD-chunked swizzle: each XCD owns one
// w2t col-panel (1 MB, L2-pinned) and streams its h1 row-panels once.
__global__ __launch_bounds__(256, 2) void ffn2_k64_kernel(const unsigned short* __restrict__ A,
                                                          const unsigned short* __restrict__ Bt,
                                                          const float* __restrict__ b2,
                                                          const float* __restrict__ x,
                                                          const int* __restrict__ topk,
                                                          float* __restrict__ out) {
    constexpr int K  = DFF_;      // 4096
    constexpr int NT = K / 64;    // 64 K-tiles
    __shared__ __align__(16) unsigned short smem[32768];   // 64 KiB: 2 x (A 8192 | B 8192 shorts)

    const int t    = threadIdx.x;
    const int lane = t & 63;
    const int wid  = t >> 6;
    const int quad = lane >> 4;
    const int lr   = lane & 15;
    const int wr   = wid >> 1;            // 0..1  (M)
    const int wc   = wid & 1;             // 0..1  (N)
    // XCD swizzle: grid 512 (1D); XCD k (bid%8) gets L in [64k,64k+64) = col-panel k, all 64 rows.
    const int L    = (blockIdx.x & 7) * 64 + (blockIdx.x >> 3);
    const int row0 = (L & 63) * 128;
    const int col0 = (L >> 6) * 128;

    const char* aS[4]; const char* bS[4]; int oA[4], oB[4];
    #pragma unroll
    for (int j = 0; j < 4; ++j) {
        int s = t + j * 256;
        int r = s >> 3, c = (s & 7) ^ (r & 7);
        aS[j] = (const char*)A  + ((size_t)(row0 + r) * K + (size_t)c * 8) * 2;
        bS[j] = (const char*)Bt + ((size_t)(col0 + r) * K + (size_t)c * 8) * 2;
        oA[j] = s * 8;
        oB[j] = 8192 + s * 8;
    }

    const int rbA = wr * 64 + lr;
    const int aoff0 = (rbA * 8 + (quad       ^ (rbA & 7))) * 8;
    const int aoff1 = (rbA * 8 + ((4 + quad) ^ (rbA & 7))) * 8;
    const int rbB = wc * 64 + lr;
    const int boff0 = 8192 + (rbB * 8 + (quad       ^ (rbB & 7))) * 8;
    const int boff1 = 8192 + (rbB * 8 + ((4 + quad) ^ (rbB & 7))) * 8;

    unsigned short* lds0 = smem;
    unsigned short* lds1 = smem + 16384;

    // ---- prologue: stage K-tile 0 ----
    #pragma unroll
    for (int j = 0; j < 4; ++j) { gld16(aS[j], lds0 + oA[j]); gld16(bS[j], lds0 + oB[j]); }
    #pragma unroll
    for (int j = 0; j < 4; ++j) { aS[j] += 128; bS[j] += 128; }
    asm volatile("s_waitcnt vmcnt(0)" ::: "memory");
    __builtin_amdgcn_s_barrier();

    float4v acc[4][4] = {};

    auto step = [&](const unsigned short* cur, unsigned short* nxt, bool pf) {
        short8 af[4], bq[4];
        #pragma unroll
        for (int mi = 0; mi < 4; ++mi) af[mi] = *(const short8*)(cur + aoff0 + mi * 1024);
        #pragma unroll
        for (int ni = 0; ni < 4; ++ni) bq[ni] = *(const short8*)(cur + boff0 + ni * 1024);
        if (pf) {
            #pragma unroll
            for (int j = 0; j < 4; ++j) { gld16(aS[j], nxt + oA[j]); gld16(bS[j], nxt + oB[j]); }
            #pragma unroll
            for (int j = 0; j < 4; ++j) { aS[j] += 128; bS[j] += 128; }
        }
        __builtin_amdgcn_sched_barrier(0);
        __builtin_amdgcn_s_setprio(1);
        #pragma unroll
        for (int mi = 0; mi < 4; ++mi)
            #pragma unroll
            for (int ni = 0; ni < 4; ++ni)
                acc[mi][ni] = __builtin_amdgcn_mfma_f32_16x16x32_bf16(af[mi], bq[ni], acc[mi][ni], 0, 0, 0);
        __builtin_amdgcn_s_setprio(0);
        #pragma unroll
        for (int mi = 0; mi < 4; ++mi) af[mi] = *(const short8*)(cur + aoff1 + mi * 1024);
        #pragma unroll
        for (int ni = 0; ni < 4; ++ni) bq[ni] = *(const short8*)(cur + boff1 + ni * 1024);
        __builtin_amdgcn_s_setprio(1);
        #pragma unroll
        for (int mi = 0; mi < 4; ++mi)
            #pragma unroll
            for (int ni = 0; ni < 4; ++ni)
                acc[mi][ni] = __builtin_amdgcn_mfma_f32_16x16x32_bf16(af[mi], bq[ni], acc[mi][ni], 0, 0, 0);
        __builtin_amdgcn_s_setprio(0);
        asm volatile("s_waitcnt vmcnt(0)" ::: "memory");
        __builtin_amdgcn_s_barrier();
    };

    for (int kt = 0; kt < NT - 2; kt += 2) { step(lds0, lds1, true); step(lds1, lds0, true); }
    step(lds0, lds1, true);    // kt = NT-2
    step(lds1, lds0, false);   // kt = NT-1

    // ---- epilogue: scattered residual stores (identical math/order to r4 ffn2) ----
    #pragma unroll
    for (int mi = 0; mi < 4; ++mi) {
        #pragma unroll
        for (int r = 0; r < 4; ++r) {
            int row = row0 + wr * 64 + mi * 16 + quad * 4 + r;
            int gb = row >> 11;
            int tok = topk[row];
            size_t base = ((size_t)(gb * N_ + tok)) * D_;
            #pragma unroll
            for (int ni = 0; ni < 4; ++ni) {
                int col = col0 + wc * 64 + ni * 16 + lr;
                out[base + col] = x[base + col] + acc[mi][ni][r] + b2[col];
            }
        }
    }
}

extern "C" void kernel_launch(void* const* d_in, const int* in_sizes, int n_in,
                              void* d_out, int out_size, void* d_ws, size_t ws_size,
                              hipStream_t stream) {
    const float* x      = (const float*)d_in[0];
    const float* gate_w = (const float*)d_in[1];
    const float* w1     = (const float*)d_in[2];
    const float* b1     = (const float*)d_in[3];
    const float* w2     = (const float*)d_in[4];
    const float* b2     = (const float*)d_in[5];
    float* out = (float*)d_out;

    char* ws = (char*)d_ws;
    float*          scores = (float*)ws;                                        // 64 KiB
    int*            topk   = (int*)(ws + (64 << 10));                           // 32 KiB
    int*            slot   = (int*)(ws + (96 << 10));                           // 64 KiB
    unsigned short* xsel   = (unsigned short*)(ws + (160 << 10));               // 16 MiB
    unsigned short* w1t    = (unsigned short*)(ws + (160 << 10) + (16 << 20));  // 8 MiB  [4096][1024]
    unsigned short* w2t    = (unsigned short*)(ws + (160 << 10) + (24 << 20));  // 8 MiB  [1024][4096]
    unsigned short* h1     = (unsigned short*)(ws + (160 << 10) + (32 << 20));  // 64 MiB [8192][4096]

    scores_kernel<<<(B_ * N_) / 4, 256, 0, stream>>>(x, gate_w, scores, slot);
    select_topk_kernel<<<B_, 1024, 0, stream>>>(scores, topk, slot);

    transpose_both_kernel<<<8192, 256, 0, stream>>>(w1, w2, w1t, w2t);

    gather_copy_kernel<<<B_ * N_, 256, 0, stream>>>(x, slot, xsel, out);

    ffn1_w128_kernel<<<1024, 256, 0, stream>>>(xsel, w1t, b1, h1);
    ffn2_k64_kernel<<<512, 256, 0, stream>>>(h1, w2t, b2, x, topk, out);
}